// Round 14
// baseline (8340.460 us; speedup 1.0000x reference)
//
#include <hip/hip_runtime.h>
#include <math.h>

// ESN reservoir: B=1, T=2048, I=8, R=4096, O=8.
// h_t = tanh(Win x_t + W h_{t-1}); y_t = Wout h_t + b.
//
// R14 = R13 (64 WGs x 1024 thr, register W-pool, per-WG flag lines) with
// the sync critical path shortened:
//  1. SPECULATIVE COMBINED READ: each lane issues its 16B h-read AND its
//     source WG's flag load in ONE asm block (16 same-address lanes
//     coalesce -> 4 flag requests/wave, 64/line/round as before). If
//     flag >= 16t the data is valid -> accept; else sleep+retry both.
//     Collapses poll-RT + data-RT into one MALL round trip.
//  2. PER-WAVE PUBLISH: flag = counter; each wave after its own 4 h-stores
//     + vmcnt(0) drain does one fire-and-forget atomicAdd(+1) (16 RMW/line
//     /step, far below R8's collapse regime). No producer barrier / tid0
//     store on the critical path. Consumers accept at flag >= 16t.
// NUMERICS BIT-IDENTICAL to R4..R13 (same entry order, shfl tree, Win/tanh,
// out-kernel). absmax 0.0078125 expected.

#define T_STEPS 2048
#define R_DIM   4096
#define I_DIM   8
#define O_DIM   8
#define NWG     64
#define ROWS_PER_WG (R_DIM / NWG)   // 64
#define HALF_ROWS 32                // rows per setup pass
#define POOL_CAP 16384              // staging for 32 rows (mean 13107 nnz)
#define BLOCK    1024               // 16 threads/row x 64 rows
#define NS       36                 // reg slots/thread (36*16=576 >= max row nnz)

typedef float v4f __attribute__((ext_vector_type(4)));

__device__ float        g_hist[(size_t)T_STEPS * R_DIM];  // 32 MB
__device__ unsigned int g_flag[NWG * 32];                 // one 128-B line per WG

__global__ void esn_init_kernel() {
    for (int i = threadIdx.x; i < NWG * 32; i += blockDim.x)
        __hip_atomic_store(&g_flag[i], 0u, __ATOMIC_RELAXED,
                           __HIP_MEMORY_SCOPE_SYSTEM);
}

__launch_bounds__(BLOCK, 1)
__global__ void esn_recur_kernel(const float* __restrict__ x,
                                 const float* __restrict__ Win,
                                 const float* __restrict__ W) {
    __shared__ uint2 s_pool[POOL_CAP];                // 128 KB staging (setup only)
    __shared__ float s_h[R_DIM];                      // 16 KB
    __shared__ int   s_start[HALF_ROWS + 1];
    __shared__ int   s_cnt[HALF_ROWS];
    __shared__ float s_win[ROWS_PER_WG][I_DIM];       // 2 KB

    const int wg   = blockIdx.x;
    const int tid  = threadIdx.x;
    const int lane = tid & 63;
    const int wave = tid >> 6;          // 0..15
    const int row0 = wg * ROWS_PER_WG;

    const int row16 = tid >> 4;          // 0..63: which of my 64 rows
    const int sub   = tid & 15;          // 16 threads per row (frozen)

    float    rv[NS];                     // per-slot values
    unsigned ri[NS / 2];                 // per-slot h byte-addresses, u16x2

    // ---------- setup: two passes of ballot compaction (as R13) ----------
    for (int pass = 0; pass < 2; ++pass) {
        const int prow0 = row0 + pass * HALF_ROWS;
        for (int rr = wave; rr < HALF_ROWS; rr += 16) {
            const float* wrow = W + (size_t)(prow0 + rr) * R_DIM;
            int cnt = 0;
            for (int base = 0; base < R_DIM; base += 64) {
                float v = wrow[base + lane];
                cnt += __popcll(__ballot(v != 0.0f));
            }
            if (lane == 0) s_cnt[rr] = cnt;
        }
        __syncthreads();
        if (tid == 0) {
            int acc = 0;
            for (int rr = 0; rr < HALF_ROWS; ++rr) {
                s_start[rr] = (acc < POOL_CAP) ? acc : POOL_CAP;
                acc += s_cnt[rr];
            }
            s_start[HALF_ROWS] = (acc < POOL_CAP) ? acc : POOL_CAP;
        }
        __syncthreads();
        for (int rr = wave; rr < HALF_ROWS; rr += 16) {
            const float* wrow = W + (size_t)(prow0 + rr) * R_DIM;
            int off = s_start[rr];
            for (int base = 0; base < R_DIM; base += 64) {
                float v = wrow[base + lane];
                unsigned long long m = __ballot(v != 0.0f);
                int pre = __popcll(m & ((1ull << lane) - 1ull));
                if (v != 0.0f) {
                    int pos = off + pre;
                    if (pos < POOL_CAP) {
                        s_pool[pos].x = __float_as_uint(v);
                        s_pool[pos].y = (base + lane) * 4;   // byte addr
                    }
                }
                off += __popcll(m);
            }
        }
        __syncthreads();
        const int lr = row16 - pass * HALF_ROWS;
        if (lr >= 0 && lr < HALF_ROWS) {
            const int st = s_start[lr];
            const int en = s_start[lr + 1];
            #pragma unroll
            for (int m = 0; m < NS; ++m) {
                const int e = st + sub + (m << 4);
                float    v = 0.0f;
                unsigned b = 0u;
                if (e < en) { uint2 p = s_pool[e]; v = __uint_as_float(p.x); b = p.y; }
                rv[m] = v;
                if ((m & 1) == 0) ri[m >> 1] = b;
                else              ri[m >> 1] |= (b << 16);
            }
        }
        __syncthreads();
    }
    if (tid < ROWS_PER_WG * I_DIM) {
        int rr = tid / I_DIM, c = tid % I_DIM;
        s_win[rr][c] = Win[(size_t)(row0 + rr) * I_DIM + c];
    }
    __syncthreads();

    // combined-read setup: this lane's 4 h values come from source WG
    // (tid>>4); its flag line is polled by the 16 lanes sharing that source
    // (coalesced to one request per wave per line).
    const unsigned* fsrc = &g_flag[(tid >> 4) << 5];

    // ---------- time loop ----------
    for (int t = 0; t < T_STEPS; ++t) {
        // prefetch x_t (issued early; same values/order)
        const float4* xp = (const float4*)(x + (size_t)t * I_DIM);
        const float4 xa = xp[0];
        const float4 xb = xp[1];

        if (t > 0) {
            const unsigned need = (unsigned)t << 4;   // 16*t
            const float* hp = g_hist + (size_t)(t - 1) * R_DIM
                              + (size_t)tid * 4;
            v4f r0; unsigned fv;
            // speculative combined read: data + source flag in one RT
            for (;;) {
                asm volatile(
                    "global_load_dwordx4 %0, %2, off sc0 sc1\n\t"
                    "global_load_dword %1, %3, off sc0 sc1\n\t"
                    "s_waitcnt vmcnt(0)"
                    : "=v"(r0), "=v"(fv)
                    : "v"(hp), "v"(fsrc)
                    : "memory");
                if (__all(fv >= need)) break;
                __builtin_amdgcn_s_sleep(2);
            }
            *(v4f*)(s_h + (size_t)tid * 4) = r0;
            __syncthreads();
        }

        // sparse row-dot from REGISTERS: slot order == stride-16 entry order
        float acc = 0.0f;
        if (t > 0) {
            #pragma unroll
            for (int m = 0; m < NS; ++m) {
                const unsigned ba = (m & 1) ? (ri[m >> 1] >> 16)
                                            : (ri[m >> 1] & 0xffffu);
                const float hv = *(const float*)((const char*)s_h + ba);
                acc += rv[m] * hv;
            }
        }
        acc += __shfl_xor(acc, 8, 16);
        acc += __shfl_xor(acc, 4, 16);
        acc += __shfl_xor(acc, 2, 16);
        acc += __shfl_xor(acc, 1, 16);

        if (sub == 0) {
            float a = acc;
            a += s_win[row16][0] * xa.x;
            a += s_win[row16][1] * xa.y;
            a += s_win[row16][2] * xa.z;
            a += s_win[row16][3] * xa.w;
            a += s_win[row16][4] * xb.x;
            a += s_win[row16][5] * xb.y;
            a += s_win[row16][6] * xb.z;
            a += s_win[row16][7] * xb.w;
            float h = tanhf(a);
            __hip_atomic_store(&g_hist[(size_t)t * R_DIM + row0 + row16], h,
                               __ATOMIC_RELAXED, __HIP_MEMORY_SCOPE_SYSTEM);
        }
        // per-wave publish: drain own h stores, then one atomicAdd(+1).
        asm volatile("s_waitcnt vmcnt(0)" ::: "memory");
        if (lane == 0)
            (void)__hip_atomic_fetch_add(&g_flag[wg << 5], 1u,
                                         __ATOMIC_RELAXED,
                                         __HIP_MEMORY_SCOPE_SYSTEM);
        __syncthreads();   // protect s_h for next iteration's deposit
    }
}

// y_t = Wout h_t + b, one wave per timestep; accumulation order as R4..R13.
__global__ void esn_out_kernel(const float* __restrict__ Wout_w,
                               const float* __restrict__ Wout_b,
                               float* __restrict__ out) {
    const int t = blockIdx.x;
    const int lane = threadIdx.x;  // 64 threads
    const float* hp = g_hist + (size_t)t * R_DIM;
    float acc[O_DIM];
    #pragma unroll
    for (int o = 0; o < O_DIM; ++o) acc[o] = 0.0f;
    for (int i = lane; i < R_DIM; i += 256) {   // 16 iters, 4 indep loads each
        float h0 = __hip_atomic_load(hp + i,       __ATOMIC_RELAXED, __HIP_MEMORY_SCOPE_SYSTEM);
        float h1 = __hip_atomic_load(hp + i + 64,  __ATOMIC_RELAXED, __HIP_MEMORY_SCOPE_SYSTEM);
        float h2 = __hip_atomic_load(hp + i + 128, __ATOMIC_RELAXED, __HIP_MEMORY_SCOPE_SYSTEM);
        float h3 = __hip_atomic_load(hp + i + 192, __ATOMIC_RELAXED, __HIP_MEMORY_SCOPE_SYSTEM);
        #pragma unroll
        for (int o = 0; o < O_DIM; ++o) acc[o] += h0 * Wout_w[(size_t)o * R_DIM + i];
        #pragma unroll
        for (int o = 0; o < O_DIM; ++o) acc[o] += h1 * Wout_w[(size_t)o * R_DIM + i + 64];
        #pragma unroll
        for (int o = 0; o < O_DIM; ++o) acc[o] += h2 * Wout_w[(size_t)o * R_DIM + i + 128];
        #pragma unroll
        for (int o = 0; o < O_DIM; ++o) acc[o] += h3 * Wout_w[(size_t)o * R_DIM + i + 192];
    }
    #pragma unroll
    for (int o = 0; o < O_DIM; ++o) {
        float a = acc[o];
        a += __shfl_xor(a, 32);
        a += __shfl_xor(a, 16);
        a += __shfl_xor(a, 8);
        a += __shfl_xor(a, 4);
        a += __shfl_xor(a, 2);
        a += __shfl_xor(a, 1);
        if (lane == 0) out[(size_t)t * O_DIM + o] = a + Wout_b[o];
    }
}

extern "C" void kernel_launch(void* const* d_in, const int* in_sizes, int n_in,
                              void* d_out, int out_size, void* d_ws, size_t ws_size,
                              hipStream_t stream) {
    const float* x    = (const float*)d_in[0];   // [1,2048,8]
    const float* Win  = (const float*)d_in[1];   // [4096,8]
    const float* W    = (const float*)d_in[2];   // [4096,4096]
    const float* Ww   = (const float*)d_in[3];   // [8,4096]
    const float* Wb   = (const float*)d_in[4];   // [8]
    float* out = (float*)d_out;                  // [1,2048,8]

    hipLaunchKernelGGL(esn_init_kernel, dim3(1), dim3(256), 0, stream);

    void* args[] = { (void*)&x, (void*)&Win, (void*)&W };
    hipLaunchCooperativeKernel((void*)esn_recur_kernel, dim3(NWG), dim3(BLOCK),
                               args, 0, stream);

    hipLaunchKernelGGL(esn_out_kernel, dim3(T_STEPS), dim3(64), 0, stream,
                       Ww, Wb, out);
}